// Round 9
// baseline (275.876 us; speedup 1.0000x reference)
//
#include <hip/hip_runtime.h>
#include <hip/hip_cooperative_groups.h>
#include <math.h>

namespace cg = cooperative_groups;

#define Bn 32
#define Cn 256
#define Hn 64
#define Wn 64
#define HWn (Hn * Wn)      // 4096
#define MIDn 16
#define Kn 7
#define PADn 3

typedef float vf4 __attribute__((ext_vector_type(4)));

// Single cooperative kernel: pool | sync | mlp+feat | sync | conv | sync | out
// grid = G blocks (<=1024) x 256 threads, __launch_bounds__(256,4) -> 4 blocks/CU.
__global__ __launch_bounds__(256, 4) void cbam_kernel(
    const float* __restrict__ x,  const float* __restrict__ w1,
    const float* __restrict__ w2, const float* __restrict__ wsp,
    float* __restrict__ avg, float* __restrict__ mx, float* __restrict__ ca,
    float* __restrict__ fmean, float* __restrict__ fmax,
    float* __restrict__ smap, float* __restrict__ out, int G)
{
    cg::grid_group grid = cg::this_grid();
    __shared__ float4 lds4[512];      // 8 KB: feat partials / conv stage
    float* ldsf = (float*)lds4;
    __shared__ float sca_s[Cn];
    __shared__ float sh_s[2 * MIDn];
    __shared__ float wgt_s[2 * Kn * Kn];

    const int t = threadIdx.x;
    const int blk = blockIdx.x;
    const int wave = t >> 6, lane = t & 63;

    // ---- Phase 1: per-(b,c) mean/max pool (one wave per plane) ----
    for (int pair = blk * 4 + wave; pair < Bn * Cn; pair += G * 4) {
        const float4* xp4 = (const float4*)(x + (size_t)pair * HWn);
        float s = 0.f, m = -INFINITY;
        #pragma unroll
        for (int k = 0; k < 16; ++k) {
            float4 v = xp4[lane + k * 64];
            s += v.x + v.y + v.z + v.w;
            m = fmaxf(m, fmaxf(fmaxf(v.x, v.y), fmaxf(v.z, v.w)));
        }
        #pragma unroll
        for (int off = 32; off > 0; off >>= 1) {
            s += __shfl_down(s, off);
            m = fmaxf(m, __shfl_down(m, off));
        }
        if (lane == 0) {
            avg[pair] = s * (1.f / (float)HWn);
            mx[pair]  = m;
        }
    }
    grid.sync();

    // ---- Phase 2: embedded MLP (per tile) + channel mean/max -> fmean/fmax ----
    // 1024 tiles of 128 pixels; threads = (32 float4-px) x (8 ch-groups of 32).
    for (int tile = blk; tile < Bn * 32; tile += G) {
        int b = tile >> 5;
        int p0 = (tile & 31) * 128;
        // MLP -> sca_s (proven R8 phase A)
        if (t < 2 * MIDn) {
            int mm = t & (MIDn - 1);
            const float4* src = (const float4*)((t < MIDn ? avg : mx) + b * Cn);
            const float4* wr = (const float4*)(w1 + mm * Cn);
            float acc = 0.f;
            #pragma unroll
            for (int c4 = 0; c4 < Cn / 4; ++c4) {
                float4 v = src[c4], w = wr[c4];
                acc += v.x * w.x + v.y * w.y + v.z * w.z + v.w * w.w;
            }
            sh_s[t] = fmaxf(acc, 0.f);         // relu
        }
        __syncthreads();
        {
            float acc = 0.f;
            #pragma unroll
            for (int mm = 0; mm < MIDn; ++mm)
                acc += (sh_s[mm] + sh_s[MIDn + mm]) * w2[t * MIDn + mm];
            sca_s[t] = 1.f / (1.f + expf(-acc));
        }
        __syncthreads();
        if ((tile & 31) == 0) ca[b * Cn + t] = sca_s[t];  // persist ca once/batch

        int tx = t & 31;                       // float4-pixel 0..31
        int ty = t >> 5;                       // ch-group 0..7
        const float* xb = x + (size_t)b * Cn * HWn + p0 + tx * 4;
        float4 s = {0.f, 0.f, 0.f, 0.f};
        float4 m = {-INFINITY, -INFINITY, -INFINITY, -INFINITY};
        int c0 = ty * 32;
        for (int c = c0; c < c0 + 32; ++c) {
            float a = sca_s[c];
            float4 v = *(const float4*)(xb + (size_t)c * HWn);
            v.x *= a; v.y *= a; v.z *= a; v.w *= a;
            s.x += v.x; s.y += v.y; s.z += v.z; s.w += v.w;
            m.x = fmaxf(m.x, v.x); m.y = fmaxf(m.y, v.y);
            m.z = fmaxf(m.z, v.z); m.w = fmaxf(m.w, v.w);
        }
        float4* lsum = (float4*)lds4;          // [8][32]
        float4* lmax = lsum + 256;
        lsum[ty * 32 + tx] = s; lmax[ty * 32 + tx] = m;
        __syncthreads();
        if (ty == 0) {
            #pragma unroll
            for (int q = 1; q < 8; ++q) {
                float4 s2 = lsum[q * 32 + tx], m2 = lmax[q * 32 + tx];
                s.x += s2.x; s.y += s2.y; s.z += s2.z; s.w += s2.w;
                m.x = fmaxf(m.x, m2.x); m.y = fmaxf(m.y, m2.y);
                m.z = fmaxf(m.z, m2.z); m.w = fmaxf(m.w, m2.w);
            }
            const float inv = 1.f / (float)Cn;
            float4 mean4 = {s.x * inv, s.y * inv, s.z * inv, s.w * inv};
            *(float4*)(fmean + b * HWn + p0 + tx * 4) = mean4;
            *(float4*)(fmax  + b * HWn + p0 + tx * 4) = m;
        }
        __syncthreads();
    }
    grid.sync();

    // ---- Phase 3: 7x7 conv + sigmoid -> smap (4-row stripes, 512 tiles) ----
    {
        float* sm = ldsf;                      // 10 rows x 64
        float* sx = ldsf + 640;
        for (int tile = blk; tile < Bn * 16; tile += G) {
            int b = tile >> 4;
            int r0 = (tile & 15) * 4;
            if (t < 2 * Kn * Kn) wgt_s[t] = wsp[t];
            for (int i = t; i < 10 * 64; i += 256) {
                int rr = r0 - PADn + (i >> 6);
                int cc = i & 63;
                float vm = 0.f, vx = 0.f;
                if (rr >= 0 && rr < Hn) {
                    vm = fmean[b * HWn + rr * Wn + cc];
                    vx = fmax[b * HWn + rr * Wn + cc];
                }
                sm[i] = vm; sx[i] = vx;
            }
            __syncthreads();
            int h = t >> 6, w = t & 63;        // local row 0..3
            float acc = 0.f;
            #pragma unroll
            for (int kh = 0; kh < Kn; ++kh) {
                #pragma unroll
                for (int kw = 0; kw < Kn; ++kw) {
                    int ww = w + kw - PADn;
                    if (ww < 0 || ww >= Wn) continue;
                    acc += sm[(h + kh) * 64 + ww] * wgt_s[kh * Kn + kw]
                         + sx[(h + kh) * 64 + ww] * wgt_s[Kn * Kn + kh * Kn + kw];
                }
            }
            smap[b * HWn + (r0 + h) * Wn + w] = 1.f / (1.f + expf(-acc));
            __syncthreads();
        }
    }
    grid.sync();

    // ---- Phase 4: out = x * ca * smap (one plane per iteration, NT store) ----
    for (int bc = blk; bc < Bn * Cn; bc += G) {
        int b = bc >> 8;
        float a = ca[bc];
        const float4* xp = (const float4*)(x + (size_t)bc * HWn);
        const float4* sp = (const float4*)(smap + (size_t)b * HWn);
        vf4* op = (vf4*)out + (size_t)bc * (HWn / 4);
        #pragma unroll
        for (int k = 0; k < 4; ++k) {
            int i = t + k * 256;
            float4 v = xp[i];
            float4 s4 = sp[i];
            vf4 o = {v.x * a * s4.x, v.y * a * s4.y, v.z * a * s4.z, v.w * a * s4.w};
            __builtin_nontemporal_store(o, op + i);
        }
    }
}

extern "C" void kernel_launch(void* const* d_in, const int* in_sizes, int n_in,
                              void* d_out, int out_size, void* d_ws, size_t ws_size,
                              hipStream_t stream) {
    const float* x  = (const float*)d_in[0];
    const float* w1 = (const float*)d_in[1];
    const float* w2 = (const float*)d_in[2];
    const float* ws = (const float*)d_in[3];
    float* out = (float*)d_out;

    float* wsf   = (float*)d_ws;
    float* avg   = wsf;                      // B*C       = 8192
    float* mx    = avg + Bn * Cn;            // 8192
    float* ca    = mx + Bn * Cn;             // 8192
    float* fmean = ca + Bn * Cn;             // B*HW      = 131072
    float* fmax  = fmean + Bn * HWn;         // 131072
    float* smap  = fmax + Bn * HWn;          // 131072

    int G = 1024;                            // 4 blocks/CU x 256 CUs
    int maxB = 0;
    if (hipOccupancyMaxActiveBlocksPerMultiprocessor(&maxB, (const void*)cbam_kernel,
                                                     256, 0) == hipSuccess && maxB > 0) {
        int g2 = maxB * 256;                 // 256 CUs on MI355X
        if (g2 < G) G = g2;
    }

    void* args[] = {(void*)&x, (void*)&w1, (void*)&w2, (void*)&ws,
                    (void*)&avg, (void*)&mx, (void*)&ca, (void*)&fmean,
                    (void*)&fmax, (void*)&smap, (void*)&out, (void*)&G};
    hipLaunchCooperativeKernel((const void*)cbam_kernel, dim3(G), dim3(256),
                               args, 0, stream);
}

// Round 10
// 100.406 us; speedup vs baseline: 2.7476x; 2.7476x over previous
//
#include <hip/hip_runtime.h>
#include <math.h>

#define Bn 32
#define Cn 256
#define Hn 64
#define Wn 64
#define HWn (Hn * Wn)      // 4096
#define MIDn 16
#define Kn 7
#define PADn 3

typedef float vf4 __attribute__((ext_vector_type(4)));

// -------- Kernel 1: per-(b,c) mean & max over H*W --------
// grid = 2048 blocks x 256 threads; ONE WAVE per (b,c) pair (4 pairs/block).
__global__ void pool_kernel(const float* __restrict__ x,
                            float* __restrict__ avg, float* __restrict__ mx) {
    int wave = threadIdx.x >> 6;
    int lane = threadIdx.x & 63;
    int pair = blockIdx.x * 4 + wave;          // (b,c) index 0..8191
    const float4* xp4 = (const float4*)(x + (size_t)pair * HWn);
    float s = 0.f, m = -INFINITY;
    #pragma unroll
    for (int k = 0; k < 16; ++k) {             // 1024 float4 / 64 lanes
        float4 v = xp4[lane + k * 64];
        s += v.x + v.y + v.z + v.w;
        m = fmaxf(m, fmaxf(fmaxf(v.x, v.y), fmaxf(v.z, v.w)));
    }
    #pragma unroll
    for (int off = 32; off > 0; off >>= 1) {
        s += __shfl_down(s, off);
        m = fmaxf(m, __shfl_down(m, off));
    }
    if (lane == 0) {
        avg[pair] = s * (1.f / (float)HWn);
        mx[pair]  = m;
    }
}

// -------- Kernel 2: per-block redundant MLP + per-pixel channel mean/max --------
// grid = B*16 = 512 blocks, 512 threads = (64 float4-pixels) x (8 ch-groups of 32).
// 16 waves/CU (vs R8's 8) for latency hiding on the strided x reads.
__global__ void featmlp_kernel(const float* __restrict__ x,
                               const float* __restrict__ avg, const float* __restrict__ mx,
                               const float* __restrict__ w1, const float* __restrict__ w2,
                               float* __restrict__ fmean, float* __restrict__ fmax,
                               float* __restrict__ ca) {
    int blk = blockIdx.x;
    int b = blk >> 4;                          // 16 blocks per batch
    int ptile = (blk & 15) * 256;              // 256 pixels per block
    int t = threadIdx.x;

    // --- Phase A: ca[b,:] in LDS (tiny, redundant per block) ---
    __shared__ float sh[2 * MIDn];
    __shared__ float sca[Cn];
    if (t < 2 * MIDn) {
        int mm = t & (MIDn - 1);
        const float4* src = (const float4*)((t < MIDn ? avg : mx) + b * Cn);
        const float4* wr = (const float4*)(w1 + mm * Cn);
        float acc = 0.f;
        #pragma unroll
        for (int c4 = 0; c4 < Cn / 4; ++c4) {
            float4 v = src[c4], w = wr[c4];
            acc += v.x * w.x + v.y * w.y + v.z * w.z + v.w * w.w;
        }
        sh[t] = fmaxf(acc, 0.f);               // relu
    }
    __syncthreads();
    if (t < Cn) {
        float acc = 0.f;
        #pragma unroll
        for (int mm = 0; mm < MIDn; ++mm)
            acc += (sh[mm] + sh[MIDn + mm]) * w2[t * MIDn + mm];
        sca[t] = 1.f / (1.f + expf(-acc));
    }
    __syncthreads();
    if ((blk & 15) == 0 && t < Cn) ca[b * Cn + t] = sca[t];  // persist once/batch

    // --- Phase B: channel mean/max of x*ca; 8-way channel split ---
    int tx = t & 63;                           // float4 index (64 * 4 = 256 pixels)
    int ty = t >> 6;                           // channel eighth 0..7 (32 ch each)
    const float* xb = x + (size_t)b * Cn * HWn + ptile + tx * 4;
    float4 s = {0.f, 0.f, 0.f, 0.f};
    float4 m = {-INFINITY, -INFINITY, -INFINITY, -INFINITY};
    int c0 = ty * 32;
    for (int c = c0; c < c0 + 32; ++c) {
        float a = sca[c];
        float4 v = *(const float4*)(xb + (size_t)c * HWn);
        v.x *= a; v.y *= a; v.z *= a; v.w *= a;
        s.x += v.x; s.y += v.y; s.z += v.z; s.w += v.w;
        m.x = fmaxf(m.x, v.x); m.y = fmaxf(m.y, v.y);
        m.z = fmaxf(m.z, v.z); m.w = fmaxf(m.w, v.w);
    }
    __shared__ float4 lsum[8][64];
    __shared__ float4 lmax[8][64];
    lsum[ty][tx] = s; lmax[ty][tx] = m;
    __syncthreads();
    if (ty == 0) {
        #pragma unroll
        for (int q = 1; q < 8; ++q) {
            float4 s2 = lsum[q][tx], m2 = lmax[q][tx];
            s.x += s2.x; s.y += s2.y; s.z += s2.z; s.w += s2.w;
            m.x = fmaxf(m.x, m2.x); m.y = fmaxf(m.y, m2.y);
            m.z = fmaxf(m.z, m2.z); m.w = fmaxf(m.w, m2.w);
        }
        const float inv = 1.f / (float)Cn;
        float4 mean4 = {s.x * inv, s.y * inv, s.z * inv, s.w * inv};
        *(float4*)(fmean + b * HWn + ptile + tx * 4) = mean4;
        *(float4*)(fmax  + b * HWn + ptile + tx * 4) = m;
    }
}

// -------- Kernel 3: 7x7 conv on [2,H,W] feat + sigmoid -> smap[B,HW] --------
// grid = B*4 = 128 blocks (16-row stripes), 256 threads; stripe+halo staged in LDS
__global__ void conv_kernel(const float* __restrict__ fmean, const float* __restrict__ fmax,
                            const float* __restrict__ wsp, float* __restrict__ smap) {
    int blk = blockIdx.x;
    int b = blk >> 2;
    int r0 = (blk & 3) * 16;
    __shared__ float sm[22][64];
    __shared__ float sx[22][64];
    __shared__ float wgt[2 * Kn * Kn];
    int t = threadIdx.x;
    if (t < 2 * Kn * Kn) wgt[t] = wsp[t];
    for (int i = t; i < 22 * 64; i += 256) {
        int rr = r0 - PADn + (i >> 6);
        int cc = i & 63;
        float vm = 0.f, vx = 0.f;
        if (rr >= 0 && rr < Hn) {
            vm = fmean[b * HWn + rr * Wn + cc];
            vx = fmax[b * HWn + rr * Wn + cc];
        }
        sm[i >> 6][cc] = vm;
        sx[i >> 6][cc] = vx;
    }
    __syncthreads();
    for (int p = t; p < 16 * Wn; p += 256) {
        int h = p >> 6, w = p & 63;           // local row 0..15
        float acc = 0.f;
        #pragma unroll
        for (int kh = 0; kh < Kn; ++kh) {
            #pragma unroll
            for (int kw = 0; kw < Kn; ++kw) {
                int ww = w + kw - PADn;
                if (ww < 0 || ww >= Wn) continue;
                acc += sm[h + kh][ww] * wgt[kh * Kn + kw]
                     + sx[h + kh][ww] * wgt[Kn * Kn + kh * Kn + kw];
            }
        }
        smap[b * HWn + (r0 + h) * Wn + w] = 1.f / (1.f + expf(-acc));
    }
}

// -------- Kernel 4: out = x * ca * smap; one (b,c) plane per block --------
// grid = B*C = 8192 blocks, 256 threads, 4 float4 per thread; ca is block-uniform.
__global__ void out_kernel(const float* __restrict__ x, const float* __restrict__ ca,
                           const float* __restrict__ smap, float* __restrict__ out) {
    int bc = blockIdx.x;
    int b = bc >> 8;
    float a = ca[bc];                          // block-uniform scalar
    const float4* xp = (const float4*)(x + (size_t)bc * HWn);
    const float4* sp = (const float4*)(smap + (size_t)b * HWn);
    vf4* op = (vf4*)out + (size_t)bc * (HWn / 4);
    int t = threadIdx.x;
    #pragma unroll
    for (int k = 0; k < 4; ++k) {
        int i = t + k * 256;
        float4 v = xp[i];
        float4 s4 = sp[i];
        vf4 o = {v.x * a * s4.x, v.y * a * s4.y, v.z * a * s4.z, v.w * a * s4.w};
        __builtin_nontemporal_store(o, op + i);
    }
}

extern "C" void kernel_launch(void* const* d_in, const int* in_sizes, int n_in,
                              void* d_out, int out_size, void* d_ws, size_t ws_size,
                              hipStream_t stream) {
    const float* x  = (const float*)d_in[0];
    const float* w1 = (const float*)d_in[1];
    const float* w2 = (const float*)d_in[2];
    const float* ws = (const float*)d_in[3];
    float* out = (float*)d_out;

    float* wsf   = (float*)d_ws;
    float* avg   = wsf;                      // B*C       = 8192
    float* mx    = avg + Bn * Cn;            // 8192
    float* ca    = mx + Bn * Cn;             // 8192
    float* fmean = ca + Bn * Cn;             // B*HW      = 131072
    float* fmax  = fmean + Bn * HWn;         // 131072
    float* smap  = fmax + Bn * HWn;          // 131072

    pool_kernel<<<2048, 256, 0, stream>>>(x, avg, mx);
    featmlp_kernel<<<Bn * 16, 512, 0, stream>>>(x, avg, mx, w1, w2, fmean, fmax, ca);
    conv_kernel<<<Bn * 4, 256, 0, stream>>>(fmean, fmax, ws, smap);
    out_kernel<<<Bn * Cn, 256, 0, stream>>>(x, ca, smap, out);
}